// Round 10
// baseline (313.568 us; speedup 1.0000x reference)
//
#include <hip/hip_runtime.h>
#include <math.h>

// nGPT attention. B=2, T=2048, C=1024, H=16, D=64.
// R20 = R18 + mgemm3 staging via global_load_lds (GEMM-path focus).
//   R19's 2-row-block attn REVERTED (DS-op theory falsified: conflicts -46%
//   but dur +10% - occupancy/serial-chain cost; attn has a ~115us structural
//   floor under this barrier-synced design). attn = R18 verbatim.
//   mgemm3 (Q/K projections, 6/7 of GEMM work): LSTR3=32 unpadded, staging
//   replaced by __builtin_amdgcn_global_load_lds w=16 - wave w stages buffer
//   w as 8x1KB linear ops (per-thread staging 16 instr -> ~0.5; staging regs
//   freed). Unpadded fragment reads are bank-conflict-free: slot =
//   (row&1)*16+quad*4 -> 8 slots x 8 lanes = b128 minimum (old pad only
//   served the deleted ds_writes). Bytes staged + MFMA order bit-identical.
//   mgemm1 (fp32-convert B staging) and mgemm_o untouched (LSTR=40).
// R18/R15 kept: QTILE=128 8-wave attn, merged split_hl3, permuted-key P
// store, base-2 softmax, DPP max+sum, load-after-barrier attn staging.

typedef short short8 __attribute__((ext_vector_type(8)));
typedef float floatx4 __attribute__((ext_vector_type(4)));

typedef const __attribute__((address_space(1))) unsigned int* gas1_u32;
typedef __attribute__((address_space(3))) unsigned int* las3_u32;

__device__ __forceinline__ void gload_lds16(const void* g, void* l) {
    __builtin_amdgcn_global_load_lds((gas1_u32)g, (las3_u32)l, 16, 0, 0);
}

__device__ __forceinline__ unsigned short bf16_rne(float x) {
    unsigned u = __float_as_uint(x);
    u += 0x7FFF + ((u >> 16) & 1);
    return (unsigned short)(u >> 16);
}

__device__ __forceinline__ unsigned cvt_pk_bf16(float lo, float hi) {
    unsigned r;
    asm("v_cvt_pk_bf16_f32 %0, %1, %2" : "=v"(r) : "v"(lo), "v"(hi));
    return r;
}

__device__ __forceinline__ floatx4 mfma_bf16(short8 a, short8 b, floatx4 c) {
    asm("v_mfma_f32_16x16x32_bf16 %0, %1, %2, %0" : "+v"(c) : "v"(a), "v"(b));
    return c;
}

// ---- DPP 16-lane butterfly reductions (VALU pipe) ----
template<int CTRL>
__device__ __forceinline__ float dpp_mov_f(float x) {
    return __int_as_float(__builtin_amdgcn_update_dpp(
        __float_as_int(x), __float_as_int(x), CTRL, 0xF, 0xF, false));
}
__device__ __forceinline__ float row_max16(float x) {
    x = fmaxf(x, dpp_mov_f<0xB1>(x));    // quad_perm(1,0,3,2)
    x = fmaxf(x, dpp_mov_f<0x4E>(x));    // quad_perm(2,3,0,1)
    x = fmaxf(x, dpp_mov_f<0x141>(x));   // row_half_mirror
    x = fmaxf(x, dpp_mov_f<0x140>(x));   // row_mirror
    return x;
}
__device__ __forceinline__ float row_sum16(float x) {
    x += dpp_mov_f<0xB1>(x);
    x += dpp_mov_f<0x4E>(x);
    x += dpp_mov_f<0x141>(x);
    x += dpp_mov_f<0x140>(x);
    return x;
}

// ------- fp32 -> bf16 hi/lo split, merged 3-input version (x, Wq, Wk) -------
__global__ __launch_bounds__(256) void split_hl3(
    const float* __restrict__ x, const float* __restrict__ Wq,
    const float* __restrict__ Wk,
    unsigned short* __restrict__ xh, unsigned short* __restrict__ xl,
    unsigned short* __restrict__ Wqh, unsigned short* __restrict__ Wql,
    unsigned short* __restrict__ Wkh, unsigned short* __restrict__ Wkl)
{
    const int bid = blockIdx.x;   // x: [0,2048) Wq: [2048,2560) Wk: [2560,3072)
    const float* src;
    unsigned short* hi;
    unsigned short* lo;
    size_t base;
    if (bid < 2048)      { src = x;  hi = xh;  lo = xl;  base = (size_t)bid * 2048; }
    else if (bid < 2560) { src = Wq; hi = Wqh; lo = Wql; base = (size_t)(bid - 2048) * 2048; }
    else                 { src = Wk; hi = Wkh; lo = Wkl; base = (size_t)(bid - 2560) * 2048; }
    size_t i = base + (size_t)threadIdx.x * 8;
    float4 f0 = *(const float4*)(src + i);
    float4 f1 = *(const float4*)(src + i + 4);
    float f[8] = {f0.x, f0.y, f0.z, f0.w, f1.x, f1.y, f1.z, f1.w};
    short8 h, l;
#pragma unroll
    for (int j = 0; j < 8; ++j) {
        unsigned short hb = bf16_rne(f[j]);
        h[j] = (short)hb;
        l[j] = (short)bf16_rne(f[j] - __uint_as_float((unsigned)hb << 16));
    }
    *(short8*)(hi + i) = h;
    *(short8*)(lo + i) = l;
}

// ---------------- MFMA GEMM bodies ----------------
#define LSTR 40    // mgemm1: padded rows (fp32-convert reg staging kept)
#define LSTR3 32   // mgemm3: unpadded (global_load_lds linear dest)

// 3-term bf16x3: C = Ah@Bh^T + Ah@Bl^T + Al@Bh^T, all inputs pre-split bf16.
// Staging: global_load_lds w=16, wave w stages buffer w (8 x 1KB per K-step).
__device__ __forceinline__ void mgemm3_body(unsigned short* lds,
    const unsigned short* __restrict__ Ah, const unsigned short* __restrict__ Al,
    const unsigned short* __restrict__ Bh, const unsigned short* __restrict__ Bl,
    float* __restrict__ Cm, int bm, int bn)
{
    constexpr int Kd = 1024, Nd = 1024;
    unsigned short* LAh = lds;
    unsigned short* LBh = lds + 128 * LSTR3;
    unsigned short* LAl = lds + 2 * 128 * LSTR3;
    unsigned short* LBl = lds + 3 * 128 * LSTR3;

    const int tid = threadIdx.x;
    const int lane = tid & 63, w = tid >> 6;
    const int n16 = lane & 15, quad = lane >> 4;
    const int m0 = (w & 1) << 6, n0 = (w >> 1) << 6;

    // wave w -> buffer w: 0=LAh(Ah,bm) 1=LBh(Bh,bn) 2=LAl(Al,bm) 3=LBl(Bl,bn)
    const unsigned short* gb =
        (w == 0) ? Ah + (size_t)bm * Kd :
        (w == 1) ? Bh + (size_t)bn * Kd :
        (w == 2) ? Al + (size_t)bm * Kd :
                   Bl + (size_t)bn * Kd;
    // lane l, op j: LDS row j*16+(l>>2), chunk l&3 (linear); src matches.
    const unsigned short* gl = gb + (size_t)(lane >> 2) * Kd + (lane & 3) * 8;
    unsigned short* ldst = lds + w * (128 * LSTR3);

    floatx4 acc[4][4];
#pragma unroll
    for (int j = 0; j < 4; ++j)
#pragma unroll
        for (int i = 0; i < 4; ++i) acc[j][i] = (floatx4){0.f, 0.f, 0.f, 0.f};

    for (int kt = 0; kt < Kd; kt += 32) {
        __syncthreads();
#pragma unroll
        for (int j = 0; j < 8; ++j)
            gload_lds16(gl + (size_t)j * 16 * Kd + kt, ldst + j * 512);
        __syncthreads();

        short8 ah[4], al[4];
#pragma unroll
        for (int i = 0; i < 4; ++i) {
            ah[i] = *(const short8*)&LAh[(m0 + i * 16 + n16) * LSTR3 + quad * 8];
            al[i] = *(const short8*)&LAl[(m0 + i * 16 + n16) * LSTR3 + quad * 8];
        }
#pragma unroll
        for (int j = 0; j < 4; ++j) {
            short8 bh = *(const short8*)&LBh[(n0 + j * 16 + n16) * LSTR3 + quad * 8];
            short8 bl = *(const short8*)&LBl[(n0 + j * 16 + n16) * LSTR3 + quad * 8];
#pragma unroll
            for (int i = 0; i < 4; ++i) {
                acc[j][i] = mfma_bf16(ah[i], bh, acc[j][i]);
                acc[j][i] = mfma_bf16(ah[i], bl, acc[j][i]);
                acc[j][i] = mfma_bf16(al[i], bh, acc[j][i]);
            }
        }
    }

#pragma unroll
    for (int j = 0; j < 4; ++j)
#pragma unroll
        for (int i = 0; i < 4; ++i) {
            float* cp = Cm + (size_t)(bm + m0 + i * 16 + quad * 4) * Nd
                        + bn + n0 + j * 16 + n16;
#pragma unroll
            for (int r = 0; r < 4; ++r)
                cp[(size_t)r * Nd] = acc[j][i][r];
        }
}

// 1-term bf16: A pre-converted bf16, W fp32 converted in staging.
template<bool OUT16>
__device__ __forceinline__ void mgemm1_body(unsigned short* lds,
    const unsigned short* __restrict__ Abf, const float* __restrict__ Wf,
    void* __restrict__ Out, int bm, int bn)
{
    constexpr int Kd = 1024, Nd = 1024;
    unsigned short* LA = lds;
    unsigned short* LB = lds + 128 * LSTR;

    const int tid = threadIdx.x;
    const int srow = tid >> 1, skc = (tid & 1) << 4;
    const unsigned short* pa = Abf + (size_t)(bm + srow) * Kd + skc;
    const float* pw = Wf + (size_t)(bn + srow) * Kd + skc;
    unsigned short* da = &LA[srow * LSTR + skc];
    unsigned short* db = &LB[srow * LSTR + skc];

    const int lane = tid & 63, w = tid >> 6;
    const int n16 = lane & 15, quad = lane >> 4;
    const int m0 = (w & 1) << 6, n0 = (w >> 1) << 6;

    floatx4 acc[4][4];
#pragma unroll
    for (int j = 0; j < 4; ++j)
#pragma unroll
        for (int i = 0; i < 4; ++i) acc[j][i] = (floatx4){0.f, 0.f, 0.f, 0.f};

    short8 ra0 = *(const short8*)(pa), ra1 = *(const short8*)(pa + 8);
    float4 w0 = *(const float4*)(pw),      w1 = *(const float4*)(pw + 4);
    float4 w2 = *(const float4*)(pw + 8),  w3 = *(const float4*)(pw + 12);

    for (int kt = 0; kt < Kd; kt += 32) {
        float fw[16];
        *(float4*)&fw[0] = w0; *(float4*)&fw[4] = w1;
        *(float4*)&fw[8] = w2; *(float4*)&fw[12] = w3;
        short8 h0, h1;
#pragma unroll
        for (int j = 0; j < 8; ++j) {
            h0[j] = (short)bf16_rne(fw[j]);
            h1[j] = (short)bf16_rne(fw[8 + j]);
        }
        __syncthreads();
        *(short8*)da = ra0; *(short8*)(da + 8) = ra1;
        *(short8*)db = h0;  *(short8*)(db + 8) = h1;
        __syncthreads();
        if (kt + 32 < Kd) {
            ra0 = *(const short8*)(pa + kt + 32); ra1 = *(const short8*)(pa + kt + 40);
            w0 = *(const float4*)(pw + kt + 32);  w1 = *(const float4*)(pw + kt + 36);
            w2 = *(const float4*)(pw + kt + 40);  w3 = *(const float4*)(pw + kt + 44);
        }
        short8 ah[4];
#pragma unroll
        for (int i = 0; i < 4; ++i)
            ah[i] = *(const short8*)&LA[(m0 + i * 16 + n16) * LSTR + quad * 8];
#pragma unroll
        for (int j = 0; j < 4; ++j) {
            short8 bh = *(const short8*)&LB[(n0 + j * 16 + n16) * LSTR + quad * 8];
#pragma unroll
            for (int i = 0; i < 4; ++i)
                acc[j][i] = mfma_bf16(ah[i], bh, acc[j][i]);
        }
    }

#pragma unroll
    for (int j = 0; j < 4; ++j)
#pragma unroll
        for (int i = 0; i < 4; ++i) {
            size_t base = (size_t)(bm + m0 + i * 16 + quad * 4) * Nd
                          + bn + n0 + j * 16 + n16;
            if (OUT16) {
                unsigned short* cp = (unsigned short*)Out + base;
#pragma unroll
                for (int r = 0; r < 4; ++r)
                    cp[(size_t)r * Nd] = bf16_rne(acc[j][i][r]);
            } else {
                float* cp = (float*)Out + base;
#pragma unroll
                for (int r = 0; r < 4; ++r)
                    cp[(size_t)r * Nd] = acc[j][i][r];
            }
        }
}

__global__ __launch_bounds__(256) void mgemm_qkv(
    const unsigned short* __restrict__ xh, const unsigned short* __restrict__ xl,
    const unsigned short* __restrict__ Wqh, const unsigned short* __restrict__ Wql,
    const unsigned short* __restrict__ Wkh, const unsigned short* __restrict__ Wkl,
    const float* __restrict__ Wv,
    float* __restrict__ Qb, float* __restrict__ Kf, unsigned short* __restrict__ Vbf)
{
    // mgemm3 uses 4*128*LSTR3 = 16384 shorts (32KB); mgemm1 uses 2*128*LSTR
    // = 10240 shorts. Array sized for the max.
    __shared__ __align__(16) unsigned short lds[4 * 128 * LSTR3];
    const int bm = blockIdx.x * 128, bn = blockIdx.y * 128;
    if (blockIdx.z == 2)      mgemm1_body<true>(lds, xh, Wv, Vbf, bm, bn);
    else if (blockIdx.z == 0) mgemm3_body(lds, xh, xl, Wqh, Wql, Qb, bm, bn);
    else                      mgemm3_body(lds, xh, xl, Wkh, Wkl, Kf, bm, bn);
}

__global__ __launch_bounds__(256) void mgemm_o(const unsigned short* __restrict__ Ybf,
    const float* __restrict__ Wo, float* __restrict__ Out)
{
    __shared__ __align__(16) unsigned short lds[2 * 128 * LSTR];   // 20 KB
    mgemm1_body<false>(lds, Ybf, Wo, Out, blockIdx.x * 128, blockIdx.y * 128);
}

// ---------------- RoPE ----------------
__global__ __launch_bounds__(256) void rope_table(float2* __restrict__ tab)
{
    int idx = blockIdx.x * 256 + threadIdx.x;   // t*32 + p
    int t = idx >> 5, p = idx & 31;
    double invf = pow(10000.0, -(double)p / 32.0);
    double sd, cd;
    sincos((double)t * invf, &sd, &cd);
    tab[idx] = make_float2((float)cd, (float)sd);
}

// One wave per (b,t,h,{q|k}); lane = d. RoPE + L2-normalize + scale.
// Q: in-place fp32 (sqrt(D)=8 and log2(e) folded -> base-2 softmax).
// K: bf16 hi|lo over its own fp32 row.
__global__ __launch_bounds__(256) void rope_norm(float* __restrict__ Q,
                                                 unsigned short* __restrict__ Khl,
                                                 const float* __restrict__ s_qk,
                                                 const float2* __restrict__ tab)
{
    constexpr int T = 2048, H = 16;
    int wid = blockIdx.x * 4 + (threadIdx.x >> 6);
    const int lane = threadIdx.x & 63;
    const int sel = wid & 1; wid >>= 1;
    const int h = wid & (H - 1); wid >>= 4;
    const int t = wid & (T - 1); wid >>= 11;
    const int b = wid;

    const size_t idx = ((size_t)(b * T + t)) * H + h;
    float v = sel ? ((const float*)Khl)[idx * 64 + lane] : Q[idx * 64 + lane];

    float2 cs2 = tab[(t << 5) + (lane >> 1)];
    const float cs = cs2.x, sn = cs2.y;

    float partner = __shfl_xor(v, 1, 64);
    float rot = (lane & 1) ? partner : -partner;
    float r = v * cs + rot * sn;

    float ssq = r * r;
#pragma unroll
    for (int off = 32; off; off >>= 1) ssq += __shfl_xor(ssq, off, 64);
    float nrm = fmaxf(sqrtf(ssq), 1e-12f);

    float scale = s_qk[h * 64 + lane] * 32.0f;   // s_qk * sqrt(C)
    if (!sel) {
        // fold sqrt(D)=8 and log2(e) into Q -> attn scores are base-2
        Q[idx * 64 + lane] = r / nrm * (scale * 8.0f * 1.44269504088896340736f);
    } else {
        float val = r / nrm * scale;
        unsigned short hi = bf16_rne(val);
        unsigned short lo = bf16_rne(val - __uint_as_float((unsigned)hi << 16));
        unsigned short* row = Khl + idx * 128;
        row[lane] = hi;
        row[64 + lane] = lo;
    }
}

// ---------------- V transpose: Vbf[t][h*64+d] -> vt[bh][d][t] (bf16) --------
// Key order PERMUTED within each 64-key block: original key k (k = t mod 64)
// is stored at position 4*(k%16) + (k/16). This matches the attn C-layout of
// QK^T (lane(quad,n16) holds scores for keys {g*16+n16, g=0..3}) so P can be
// packed and written as one ds_write_b64 per row. PV contracts P and V over
// the same permuted storage index -> result unchanged.
__global__ __launch_bounds__(256) void vtrans(const unsigned short* __restrict__ Vbf,
                                              unsigned short* __restrict__ vt)
{
    constexpr int T = 2048, C = 1024;
    __shared__ unsigned short tile[64 * 72];
    const int bh = blockIdx.y;
    const int h = bh & 15, b = bh >> 4;
    const int t0 = blockIdx.x * 64;

    const int tl = threadIdx.x & 63;
    const int dc = threadIdx.x >> 6;
    const int ptl = ((tl & 15) << 2) | (tl >> 4);   // permuted key position
    const unsigned short* src = Vbf + (size_t)(b * T + t0 + tl) * C + h * 64 + dc * 16;
    short8 s0 = *(const short8*)src;
    short8 s1 = *(const short8*)(src + 8);
#pragma unroll
    for (int j = 0; j < 8; ++j) tile[(dc * 16 + j) * 72 + ptl] = (unsigned short)s0[j];
#pragma unroll
    for (int j = 0; j < 8; ++j) tile[(dc * 16 + 8 + j) * 72 + ptl] = (unsigned short)s1[j];
    __syncthreads();

    const int d = threadIdx.x >> 2;
    const int tc = threadIdx.x & 3;
    short8 r0 = *(const short8*)&tile[d * 72 + tc * 16];
    short8 r1 = *(const short8*)&tile[d * 72 + tc * 16 + 8];
    unsigned short* dst = vt + ((size_t)bh * 64 + d) * T + t0 + tc * 16;
    *(short8*)dst = r0;
    *(short8*)(dst + 8) = r1;
}

// ---------------- MFMA flash attention ----------------
// R18 verbatim: QTILE=128, 8 waves (512 threads); KTL=64 keys/tile. K/V
// staged in LDS (load-after-barrier, spread over 512 threads); base-2
// softmax (log2e pre-folded into Q), DPP max+sum, cvt_pk_bf16 P rounding.
#define QTILE 128
#define KTL 64
#define KSTR 72

__global__ __launch_bounds__(512) void attn_mfma(const float* __restrict__ Q,
    const unsigned short* __restrict__ Khl, const unsigned short* __restrict__ vt,
    unsigned short* __restrict__ Ybf)
{
    constexpr int T = 2048, C = 1024;
    __shared__ __align__(16) unsigned short Ks_hi[KTL * KSTR];
    __shared__ __align__(16) unsigned short Ks_lo[KTL * KSTR];
    __shared__ __align__(16) unsigned short Vt[64 * KSTR];
    __shared__ __align__(16) unsigned short Ps[8][16 * KSTR];

    const int bh = blockIdx.y;
    const int h = bh & 15;
    const int b = bh >> 4;
    const int w = threadIdx.x >> 6;     // 0..7
    const int lane = threadIdx.x & 63;
    const int n16 = lane & 15;
    const int quad = lane >> 4;

    // Q A-fragments (hi/lo), loaded once and split.
    const int qrow = blockIdx.x * QTILE + w * 16 + n16;
    short8 qh[2], ql[2];
#pragma unroll
    for (int c = 0; c < 2; ++c) {
        const float* p = Q + ((size_t)(b * T + qrow)) * C + h * 64 + c * 32 + quad * 8;
        float4 f0 = *(const float4*)p;
        float4 f1 = *(const float4*)(p + 4);
        float f[8] = {f0.x, f0.y, f0.z, f0.w, f1.x, f1.y, f1.z, f1.w};
#pragma unroll
        for (int j = 0; j < 8; ++j) {
            unsigned short hb = bf16_rne(f[j]);
            float hf = __uint_as_float((unsigned)hb << 16);
            qh[c][j] = (short)hb;
            ql[c][j] = (short)bf16_rne(f[j] - hf);
        }
    }

    floatx4 o0 = {0,0,0,0}, o1 = {0,0,0,0}, o2 = {0,0,0,0}, o3 = {0,0,0,0};
    float mrow[4] = {-1e30f, -1e30f, -1e30f, -1e30f};
    float lrow[4] = {0.f, 0.f, 0.f, 0.f};

    // staging maps: 64 K rows (hi+lo) and 64 V dims over 512 threads,
    // 8-short chunks (1 b128 per buffer per thread)
    const unsigned short* khl = Khl + (((size_t)b * T) * 16 + h) * 128;
    const unsigned short* vtb = vt + (size_t)bh * 64 * T;
    const int sr = threadIdx.x >> 3;        // 0..63 (k-row / v-dim)
    const int sc = (threadIdx.x & 7) * 8;   // 0,8,...,56
    unsigned short* Pw = Ps[w];

    for (int kt = 0; kt < T; kt += KTL) {
        __syncthreads();
        {
            const unsigned short* src = khl + (size_t)(kt + sr) * 2048 + sc;
            *(short8*)&Ks_hi[sr * KSTR + sc] = *(const short8*)src;
            *(short8*)&Ks_lo[sr * KSTR + sc] = *(const short8*)(src + 64);
            const unsigned short* vsrc = vtb + (size_t)sr * T + kt + sc;
            *(short8*)&Vt[sr * KSTR + sc]    = *(const short8*)vsrc;
        }
        __syncthreads();

        // QK^T: 4 key groups x (2 chunks x 3 split-terms)
        floatx4 s0 = {0,0,0,0}, s1 = {0,0,0,0}, s2 = {0,0,0,0}, s3 = {0,0,0,0};
#pragma unroll
        for (int c = 0; c < 2; ++c) {
            const int ko = c * 32 + quad * 8;
            short8 kh, kl;
            kh = *(const short8*)&Ks_hi[n16 * KSTR + ko];
            kl = *(const short8*)&Ks_lo[n16 * KSTR + ko];
            s0 = mfma_bf16(qh[c], kh, s0); s0 = mfma_bf16(qh[c], kl, s0); s0 = mfma_bf16(ql[c], kh, s0);
            kh = *(const short8*)&Ks_hi[(16 + n16) * KSTR + ko];
            kl = *(const short8*)&Ks_lo[(16 + n16) * KSTR + ko];
            s1 = mfma_bf16(qh[c], kh, s1); s1 = mfma_bf16(qh[c], kl, s1); s1 = mfma_bf16(ql[c], kh, s1);
            kh = *(const short8*)&Ks_hi[(32 + n16) * KSTR + ko];
            kl = *(const short8*)&Ks_lo[(32 + n16) * KSTR + ko];
            s2 = mfma_bf16(qh[c], kh, s2); s2 = mfma_bf16(qh[c], kl, s2); s2 = mfma_bf16(ql[c], kh, s2);
            kh = *(const short8*)&Ks_hi[(48 + n16) * KSTR + ko];
            kl = *(const short8*)&Ks_lo[(48 + n16) * KSTR + ko];
            s3 = mfma_bf16(qh[c], kh, s3); s3 = mfma_bf16(qh[c], kl, s3); s3 = mfma_bf16(ql[c], kh, s3);
        }

        // online softmax, base-2 (log2e folded into Q): exp2 via v_exp_f32.
        // P for row (quad*4+r): scores for keys {g*16+n16} land at storage
        // column 4*n16+g -> 4 consecutive shorts -> packed b64 write.
#pragma unroll
        for (int r = 0; r < 4; ++r) {
            float mx = fmaxf(fmaxf(s0[r], s1[r]), fmaxf(s2[r], s3[r]));
            mx = row_max16(mx);
            float mn = fmaxf(mrow[r], mx);
            float fac = __builtin_amdgcn_exp2f(mrow[r] - mn);
            mrow[r] = mn;
            float p0 = __builtin_amdgcn_exp2f(s0[r] - mn);
            float p1 = __builtin_amdgcn_exp2f(s1[r] - mn);
            float p2 = __builtin_amdgcn_exp2f(s2[r] - mn);
            float p3 = __builtin_amdgcn_exp2f(s3[r] - mn);
            float s = row_sum16(((p0 + p1) + (p2 + p3)));
            lrow[r] = lrow[r] * fac + s;
            o0[r] *= fac; o1[r] *= fac; o2[r] *= fac; o3[r] *= fac;
            uint2 pk;
            pk.x = cvt_pk_bf16(p0, p1);
            pk.y = cvt_pk_bf16(p2, p3);
            *(uint2*)&Pw[(quad * 4 + r) * KSTR + (n16 << 2)] = pk;
        }

        // PV: keys 0..31 via pa0, 32..63 via pa1 (permuted storage order,
        // matching permuted V columns)
        {
            short8 pa0 = *(const short8*)&Pw[n16 * KSTR + quad * 8];
            short8 pa1 = *(const short8*)&Pw[n16 * KSTR + 32 + quad * 8];
            short8 v0, v1;
            v0 = *(const short8*)&Vt[n16 * KSTR + quad * 8];
            v1 = *(const short8*)&Vt[n16 * KSTR + 32 + quad * 8];
            o0 = mfma_bf16(pa0, v0, o0); o0 = mfma_bf16(pa1, v1, o0);
            v0 = *(const short8*)&Vt[(16 + n16) * KSTR + quad * 8];
            v1 = *(const short8*)&Vt[(16 + n16) * KSTR + 32 + quad * 8];
            o1 = mfma_bf16(pa0, v0, o1); o1 = mfma_bf16(pa1, v1, o1);
            v0 = *(const short8*)&Vt[(32 + n16) * KSTR + quad * 8];
            v1 = *(const short8*)&Vt[(32 + n16) * KSTR + 32 + quad * 8];
            o2 = mfma_bf16(pa0, v0, o2); o2 = mfma_bf16(pa1, v1, o2);
            v0 = *(const short8*)&Vt[(48 + n16) * KSTR + quad * 8];
            v1 = *(const short8*)&Vt[(48 + n16) * KSTR + 32 + quad * 8];
            o3 = mfma_bf16(pa0, v0, o3); o3 = mfma_bf16(pa1, v1, o3);
        }
    }

    // epilogue: normalize, write Y as bf16
#pragma unroll
    for (int r = 0; r < 4; ++r) {
        float inv = 1.0f / lrow[r];
        int row = blockIdx.x * QTILE + w * 16 + quad * 4 + r;
        unsigned short* yp = Ybf + (size_t)(b * T + row) * C + h * 64 + n16;
        yp[0]  = bf16_rne(o0[r] * inv);
        yp[16] = bf16_rne(o1[r] * inv);
        yp[32] = bf16_rne(o2[r] * inv);
        yp[48] = bf16_rne(o3[r] * inv);
    }
}

extern "C" void kernel_launch(void* const* d_in, const int* in_sizes, int n_in,
                              void* d_out, int out_size, void* d_ws, size_t ws_size,
                              hipStream_t stream)
{
    const float* x    = (const float*)d_in[0];
    const float* Wq   = (const float*)d_in[1];
    const float* Wk   = (const float*)d_in[2];
    const float* Wv   = (const float*)d_in[3];
    const float* Wo   = (const float*)d_in[4];
    const float* s_qk = (const float*)d_in[5];
    float* out = (float*)d_out;

    constexpr int B = 2, T = 2048, C = 1024, H = 16;
    constexpr int M = B * T;

    // workspace map (64 MB, phase-aliased):
    //  [0,16M)   Qb fp32 (rope in place)
    //  [16,32M)  Kf fp32 -> Khl bf16 hi|lo (rope, in place)
    //  [32,40M)  Vbf bf16 [t][C]
    //  [40,48M)  xh (dies after mgemm_qkv) -> tab (rope) -> vt [bh][d][t]
    //  [48,56M)  xl (dies after mgemm_qkv) -> Ybf bf16
    //  [56,64M)  Wqh,Wql,Wkh,Wkl (die after mgemm_qkv)
    char* ws = (char*)d_ws;
    float* Qb           = (float*)ws;
    float* Kf           = (float*)(ws + ((size_t)16 << 20));
    unsigned short* Khl = (unsigned short*)Kf;
    unsigned short* Vbf = (unsigned short*)(ws + ((size_t)32 << 20));
    unsigned short* xh  = (unsigned short*)(ws + ((size_t)40 << 20));
    unsigned short* xl  = (unsigned short*)(ws + ((size_t)48 << 20));
    unsigned short* vt  = xh;                     // after mgemm_qkv
    unsigned short* Ybf = xl;                     // after mgemm_qkv
    float2* tab         = (float2*)xh;            // between mgemm_qkv and vtrans
    unsigned short* Wqh = (unsigned short*)(ws + ((size_t)56 << 20));
    unsigned short* Wql = Wqh + (1u << 20);
    unsigned short* Wkh = Wql + (1u << 20);
    unsigned short* Wkl = Wkh + (1u << 20);

    dim3 blk(256);

    split_hl3<<<dim3(3072), blk, 0, stream>>>(x, Wq, Wk, xh, xl,
                                              Wqh, Wql, Wkh, Wkl);

    mgemm_qkv<<<dim3(M / 128, C / 128, 3), blk, 0, stream>>>(
        xh, xl, Wqh, Wql, Wkh, Wkl, Wv, Qb, Kf, Vbf);

    rope_table<<<dim3(T * 32 / 256), blk, 0, stream>>>(tab);
    rope_norm<<<dim3(2 * B * T * H / 4), blk, 0, stream>>>(Qb, Khl, s_qk, tab);
    vtrans<<<dim3(T / 64, B * H), blk, 0, stream>>>(Vbf, vt);

    attn_mfma<<<dim3(T / QTILE, B * H), dim3(512), 0, stream>>>(Qb, Khl, vt, Ybf);

    mgemm_o<<<dim3(M / 128, C / 128), blk, 0, stream>>>(Ybf, Wo, out);
}

// Round 11
// 307.598 us; speedup vs baseline: 1.0194x; 1.0194x over previous
//
#include <hip/hip_runtime.h>
#include <math.h>

// nGPT attention. B=2, T=2048, C=1024, H=16, D=64.
// R21 = R20 + double-buffered gload_lds staging in mgemm3 (fixes R20's
// diagnosed regression: load-after-barrier exposed full L2 latency that
// R18's register prefetch used to hide).
//   mgemm3: 2 x 32KB LDS buffers, ONE barrier per K-step. Iteration:
//   barrier (drains in-flight loads for buf[cur] + prior reads of
//   buf[cur^1]) -> issue next tile's 8 gload_lds into buf[cur^1] -> 48
//   MFMAs from buf[cur]. Loads fly under compute (guide 5 canonical dbuf,
//   m99/m100-verified pattern). DS ops/thread 24 (R18) -> 16; barriers
//   2 -> 1 per K-step. LDS 64KB -> 2 blocks/CU (DS-throughput regime,
//   latency covered by dbuf). Staged bytes + MFMA order bit-identical.
//   mgemm1 (fp32-convert staging) and mgemm_o untouched.
// attn = R18 verbatim (~115us structural floor; prefetch/V-direct/2-block
// families all failed or regressed - see R12-R19 postmortems).
// R18/R15 kept: QTILE=128 8-wave attn, merged split_hl3, permuted-key P
// store, base-2 softmax, DPP max+sum, load-after-barrier attn staging.

typedef short short8 __attribute__((ext_vector_type(8)));
typedef float floatx4 __attribute__((ext_vector_type(4)));

typedef const __attribute__((address_space(1))) unsigned int* gas1_u32;
typedef __attribute__((address_space(3))) unsigned int* las3_u32;

__device__ __forceinline__ void gload_lds16(const void* g, void* l) {
    __builtin_amdgcn_global_load_lds((gas1_u32)g, (las3_u32)l, 16, 0, 0);
}

__device__ __forceinline__ unsigned short bf16_rne(float x) {
    unsigned u = __float_as_uint(x);
    u += 0x7FFF + ((u >> 16) & 1);
    return (unsigned short)(u >> 16);
}

__device__ __forceinline__ unsigned cvt_pk_bf16(float lo, float hi) {
    unsigned r;
    asm("v_cvt_pk_bf16_f32 %0, %1, %2" : "=v"(r) : "v"(lo), "v"(hi));
    return r;
}

__device__ __forceinline__ floatx4 mfma_bf16(short8 a, short8 b, floatx4 c) {
    asm("v_mfma_f32_16x16x32_bf16 %0, %1, %2, %0" : "+v"(c) : "v"(a), "v"(b));
    return c;
}

// ---- DPP 16-lane butterfly reductions (VALU pipe) ----
template<int CTRL>
__device__ __forceinline__ float dpp_mov_f(float x) {
    return __int_as_float(__builtin_amdgcn_update_dpp(
        __float_as_int(x), __float_as_int(x), CTRL, 0xF, 0xF, false));
}
__device__ __forceinline__ float row_max16(float x) {
    x = fmaxf(x, dpp_mov_f<0xB1>(x));    // quad_perm(1,0,3,2)
    x = fmaxf(x, dpp_mov_f<0x4E>(x));    // quad_perm(2,3,0,1)
    x = fmaxf(x, dpp_mov_f<0x141>(x));   // row_half_mirror
    x = fmaxf(x, dpp_mov_f<0x140>(x));   // row_mirror
    return x;
}
__device__ __forceinline__ float row_sum16(float x) {
    x += dpp_mov_f<0xB1>(x);
    x += dpp_mov_f<0x4E>(x);
    x += dpp_mov_f<0x141>(x);
    x += dpp_mov_f<0x140>(x);
    return x;
}

// ------- fp32 -> bf16 hi/lo split, merged 3-input version (x, Wq, Wk) -------
__global__ __launch_bounds__(256) void split_hl3(
    const float* __restrict__ x, const float* __restrict__ Wq,
    const float* __restrict__ Wk,
    unsigned short* __restrict__ xh, unsigned short* __restrict__ xl,
    unsigned short* __restrict__ Wqh, unsigned short* __restrict__ Wql,
    unsigned short* __restrict__ Wkh, unsigned short* __restrict__ Wkl)
{
    const int bid = blockIdx.x;   // x: [0,2048) Wq: [2048,2560) Wk: [2560,3072)
    const float* src;
    unsigned short* hi;
    unsigned short* lo;
    size_t base;
    if (bid < 2048)      { src = x;  hi = xh;  lo = xl;  base = (size_t)bid * 2048; }
    else if (bid < 2560) { src = Wq; hi = Wqh; lo = Wql; base = (size_t)(bid - 2048) * 2048; }
    else                 { src = Wk; hi = Wkh; lo = Wkl; base = (size_t)(bid - 2560) * 2048; }
    size_t i = base + (size_t)threadIdx.x * 8;
    float4 f0 = *(const float4*)(src + i);
    float4 f1 = *(const float4*)(src + i + 4);
    float f[8] = {f0.x, f0.y, f0.z, f0.w, f1.x, f1.y, f1.z, f1.w};
    short8 h, l;
#pragma unroll
    for (int j = 0; j < 8; ++j) {
        unsigned short hb = bf16_rne(f[j]);
        h[j] = (short)hb;
        l[j] = (short)bf16_rne(f[j] - __uint_as_float((unsigned)hb << 16));
    }
    *(short8*)(hi + i) = h;
    *(short8*)(lo + i) = l;
}

// ---------------- MFMA GEMM bodies ----------------
#define LSTR 40    // mgemm1: padded rows (fp32-convert reg staging kept)
#define LSTR3 32   // mgemm3: unpadded (global_load_lds linear dest)
#define BUF3 (4 * 128 * LSTR3)   // 16384 shorts = 32KB per dbuf half

// 3-term bf16x3: C = Ah@Bh^T + Ah@Bl^T + Al@Bh^T, all inputs pre-split bf16.
// Staging: global_load_lds w=16, wave w stages buffer w; double-buffered,
// one barrier per K-step, loads for tile k+1 fly under tile k's MFMAs.
__device__ __forceinline__ void mgemm3_body(unsigned short* lds,
    const unsigned short* __restrict__ Ah, const unsigned short* __restrict__ Al,
    const unsigned short* __restrict__ Bh, const unsigned short* __restrict__ Bl,
    float* __restrict__ Cm, int bm, int bn)
{
    constexpr int Kd = 1024, Nd = 1024;

    const int tid = threadIdx.x;
    const int lane = tid & 63, w = tid >> 6;
    const int n16 = lane & 15, quad = lane >> 4;
    const int m0 = (w & 1) << 6, n0 = (w >> 1) << 6;

    // wave w -> buffer w: 0=LAh(Ah,bm) 1=LBh(Bh,bn) 2=LAl(Al,bm) 3=LBl(Bl,bn)
    const unsigned short* gb =
        (w == 0) ? Ah + (size_t)bm * Kd :
        (w == 1) ? Bh + (size_t)bn * Kd :
        (w == 2) ? Al + (size_t)bm * Kd :
                   Bl + (size_t)bn * Kd;
    // lane l, op j: LDS row j*16+(l>>2), chunk l&3 (linear); src matches.
    const unsigned short* gl = gb + (size_t)(lane >> 2) * Kd + (lane & 3) * 8;
    unsigned short* ldst = lds + w * (128 * LSTR3);

    floatx4 acc[4][4];
#pragma unroll
    for (int j = 0; j < 4; ++j)
#pragma unroll
        for (int i = 0; i < 4; ++i) acc[j][i] = (floatx4){0.f, 0.f, 0.f, 0.f};

    // prologue: issue tile 0 into dbuf half 0
#pragma unroll
    for (int j = 0; j < 8; ++j)
        gload_lds16(gl + (size_t)j * 16 * Kd, ldst + j * 512);

    int cur = 0;
    for (int kt = 0; kt < Kd; kt += 32) {
        __syncthreads();   // drains vmcnt (buf[cur] loads landed) + lgkm
                           // (prior iteration's reads of buf[cur^1] done)
        if (kt + 32 < Kd) {
#pragma unroll
            for (int j = 0; j < 8; ++j)
                gload_lds16(gl + (size_t)j * 16 * Kd + kt + 32,
                            ldst + (cur ^ 1) * BUF3 + j * 512);
        }
        const unsigned short* LAh = lds + cur * BUF3;
        const unsigned short* LBh = LAh + 128 * LSTR3;
        const unsigned short* LAl = LAh + 2 * 128 * LSTR3;
        const unsigned short* LBl = LAh + 3 * 128 * LSTR3;

        short8 ah[4], al[4];
#pragma unroll
        for (int i = 0; i < 4; ++i) {
            ah[i] = *(const short8*)&LAh[(m0 + i * 16 + n16) * LSTR3 + quad * 8];
            al[i] = *(const short8*)&LAl[(m0 + i * 16 + n16) * LSTR3 + quad * 8];
        }
#pragma unroll
        for (int j = 0; j < 4; ++j) {
            short8 bh = *(const short8*)&LBh[(n0 + j * 16 + n16) * LSTR3 + quad * 8];
            short8 bl = *(const short8*)&LBl[(n0 + j * 16 + n16) * LSTR3 + quad * 8];
#pragma unroll
            for (int i = 0; i < 4; ++i) {
                acc[j][i] = mfma_bf16(ah[i], bh, acc[j][i]);
                acc[j][i] = mfma_bf16(ah[i], bl, acc[j][i]);
                acc[j][i] = mfma_bf16(al[i], bh, acc[j][i]);
            }
        }
        cur ^= 1;
    }

#pragma unroll
    for (int j = 0; j < 4; ++j)
#pragma unroll
        for (int i = 0; i < 4; ++i) {
            float* cp = Cm + (size_t)(bm + m0 + i * 16 + quad * 4) * Nd
                        + bn + n0 + j * 16 + n16;
#pragma unroll
            for (int r = 0; r < 4; ++r)
                cp[(size_t)r * Nd] = acc[j][i][r];
        }
}

// 1-term bf16: A pre-converted bf16, W fp32 converted in staging.
template<bool OUT16>
__device__ __forceinline__ void mgemm1_body(unsigned short* lds,
    const unsigned short* __restrict__ Abf, const float* __restrict__ Wf,
    void* __restrict__ Out, int bm, int bn)
{
    constexpr int Kd = 1024, Nd = 1024;
    unsigned short* LA = lds;
    unsigned short* LB = lds + 128 * LSTR;

    const int tid = threadIdx.x;
    const int srow = tid >> 1, skc = (tid & 1) << 4;
    const unsigned short* pa = Abf + (size_t)(bm + srow) * Kd + skc;
    const float* pw = Wf + (size_t)(bn + srow) * Kd + skc;
    unsigned short* da = &LA[srow * LSTR + skc];
    unsigned short* db = &LB[srow * LSTR + skc];

    const int lane = tid & 63, w = tid >> 6;
    const int n16 = lane & 15, quad = lane >> 4;
    const int m0 = (w & 1) << 6, n0 = (w >> 1) << 6;

    floatx4 acc[4][4];
#pragma unroll
    for (int j = 0; j < 4; ++j)
#pragma unroll
        for (int i = 0; i < 4; ++i) acc[j][i] = (floatx4){0.f, 0.f, 0.f, 0.f};

    short8 ra0 = *(const short8*)(pa), ra1 = *(const short8*)(pa + 8);
    float4 w0 = *(const float4*)(pw),      w1 = *(const float4*)(pw + 4);
    float4 w2 = *(const float4*)(pw + 8),  w3 = *(const float4*)(pw + 12);

    for (int kt = 0; kt < Kd; kt += 32) {
        float fw[16];
        *(float4*)&fw[0] = w0; *(float4*)&fw[4] = w1;
        *(float4*)&fw[8] = w2; *(float4*)&fw[12] = w3;
        short8 h0, h1;
#pragma unroll
        for (int j = 0; j < 8; ++j) {
            h0[j] = (short)bf16_rne(fw[j]);
            h1[j] = (short)bf16_rne(fw[8 + j]);
        }
        __syncthreads();
        *(short8*)da = ra0; *(short8*)(da + 8) = ra1;
        *(short8*)db = h0;  *(short8*)(db + 8) = h1;
        __syncthreads();
        if (kt + 32 < Kd) {
            ra0 = *(const short8*)(pa + kt + 32); ra1 = *(const short8*)(pa + kt + 40);
            w0 = *(const float4*)(pw + kt + 32);  w1 = *(const float4*)(pw + kt + 36);
            w2 = *(const float4*)(pw + kt + 40);  w3 = *(const float4*)(pw + kt + 44);
        }
        short8 ah[4];
#pragma unroll
        for (int i = 0; i < 4; ++i)
            ah[i] = *(const short8*)&LA[(m0 + i * 16 + n16) * LSTR + quad * 8];
#pragma unroll
        for (int j = 0; j < 4; ++j) {
            short8 bh = *(const short8*)&LB[(n0 + j * 16 + n16) * LSTR + quad * 8];
#pragma unroll
            for (int i = 0; i < 4; ++i)
                acc[j][i] = mfma_bf16(ah[i], bh, acc[j][i]);
        }
    }

#pragma unroll
    for (int j = 0; j < 4; ++j)
#pragma unroll
        for (int i = 0; i < 4; ++i) {
            size_t base = (size_t)(bm + m0 + i * 16 + quad * 4) * Nd
                          + bn + n0 + j * 16 + n16;
            if (OUT16) {
                unsigned short* cp = (unsigned short*)Out + base;
#pragma unroll
                for (int r = 0; r < 4; ++r)
                    cp[(size_t)r * Nd] = bf16_rne(acc[j][i][r]);
            } else {
                float* cp = (float*)Out + base;
#pragma unroll
                for (int r = 0; r < 4; ++r)
                    cp[(size_t)r * Nd] = acc[j][i][r];
            }
        }
}

__global__ __launch_bounds__(256) void mgemm_qkv(
    const unsigned short* __restrict__ xh, const unsigned short* __restrict__ xl,
    const unsigned short* __restrict__ Wqh, const unsigned short* __restrict__ Wql,
    const unsigned short* __restrict__ Wkh, const unsigned short* __restrict__ Wkl,
    const float* __restrict__ Wv,
    float* __restrict__ Qb, float* __restrict__ Kf, unsigned short* __restrict__ Vbf)
{
    // mgemm3: 2 x 32KB dbuf halves = 64KB. mgemm1 uses first 20.5KB.
    __shared__ __align__(16) unsigned short lds[2 * BUF3];
    const int bm = blockIdx.x * 128, bn = blockIdx.y * 128;
    if (blockIdx.z == 2)      mgemm1_body<true>(lds, xh, Wv, Vbf, bm, bn);
    else if (blockIdx.z == 0) mgemm3_body(lds, xh, xl, Wqh, Wql, Qb, bm, bn);
    else                      mgemm3_body(lds, xh, xl, Wkh, Wkl, Kf, bm, bn);
}

__global__ __launch_bounds__(256) void mgemm_o(const unsigned short* __restrict__ Ybf,
    const float* __restrict__ Wo, float* __restrict__ Out)
{
    __shared__ __align__(16) unsigned short lds[2 * 128 * LSTR];   // 20 KB
    mgemm1_body<false>(lds, Ybf, Wo, Out, blockIdx.x * 128, blockIdx.y * 128);
}

// ---------------- RoPE ----------------
__global__ __launch_bounds__(256) void rope_table(float2* __restrict__ tab)
{
    int idx = blockIdx.x * 256 + threadIdx.x;   // t*32 + p
    int t = idx >> 5, p = idx & 31;
    double invf = pow(10000.0, -(double)p / 32.0);
    double sd, cd;
    sincos((double)t * invf, &sd, &cd);
    tab[idx] = make_float2((float)cd, (float)sd);
}

// One wave per (b,t,h,{q|k}); lane = d. RoPE + L2-normalize + scale.
// Q: in-place fp32 (sqrt(D)=8 and log2(e) folded -> base-2 softmax).
// K: bf16 hi|lo over its own fp32 row.
__global__ __launch_bounds__(256) void rope_norm(float* __restrict__ Q,
                                                 unsigned short* __restrict__ Khl,
                                                 const float* __restrict__ s_qk,
                                                 const float2* __restrict__ tab)
{
    constexpr int T = 2048, H = 16;
    int wid = blockIdx.x * 4 + (threadIdx.x >> 6);
    const int lane = threadIdx.x & 63;
    const int sel = wid & 1; wid >>= 1;
    const int h = wid & (H - 1); wid >>= 4;
    const int t = wid & (T - 1); wid >>= 11;
    const int b = wid;

    const size_t idx = ((size_t)(b * T + t)) * H + h;
    float v = sel ? ((const float*)Khl)[idx * 64 + lane] : Q[idx * 64 + lane];

    float2 cs2 = tab[(t << 5) + (lane >> 1)];
    const float cs = cs2.x, sn = cs2.y;

    float partner = __shfl_xor(v, 1, 64);
    float rot = (lane & 1) ? partner : -partner;
    float r = v * cs + rot * sn;

    float ssq = r * r;
#pragma unroll
    for (int off = 32; off; off >>= 1) ssq += __shfl_xor(ssq, off, 64);
    float nrm = fmaxf(sqrtf(ssq), 1e-12f);

    float scale = s_qk[h * 64 + lane] * 32.0f;   // s_qk * sqrt(C)
    if (!sel) {
        // fold sqrt(D)=8 and log2(e) into Q -> attn scores are base-2
        Q[idx * 64 + lane] = r / nrm * (scale * 8.0f * 1.44269504088896340736f);
    } else {
        float val = r / nrm * scale;
        unsigned short hi = bf16_rne(val);
        unsigned short lo = bf16_rne(val - __uint_as_float((unsigned)hi << 16));
        unsigned short* row = Khl + idx * 128;
        row[lane] = hi;
        row[64 + lane] = lo;
    }
}

// ---------------- V transpose: Vbf[t][h*64+d] -> vt[bh][d][t] (bf16) --------
// Key order PERMUTED within each 64-key block: original key k (k = t mod 64)
// is stored at position 4*(k%16) + (k/16). This matches the attn C-layout of
// QK^T (lane(quad,n16) holds scores for keys {g*16+n16, g=0..3}) so P can be
// packed and written as one ds_write_b64 per row. PV contracts P and V over
// the same permuted storage index -> result unchanged.
__global__ __launch_bounds__(256) void vtrans(const unsigned short* __restrict__ Vbf,
                                              unsigned short* __restrict__ vt)
{
    constexpr int T = 2048, C = 1024;
    __shared__ unsigned short tile[64 * 72];
    const int bh = blockIdx.y;
    const int h = bh & 15, b = bh >> 4;
    const int t0 = blockIdx.x * 64;

    const int tl = threadIdx.x & 63;
    const int dc = threadIdx.x >> 6;
    const int ptl = ((tl & 15) << 2) | (tl >> 4);   // permuted key position
    const unsigned short* src = Vbf + (size_t)(b * T + t0 + tl) * C + h * 64 + dc * 16;
    short8 s0 = *(const short8*)src;
    short8 s1 = *(const short8*)(src + 8);
#pragma unroll
    for (int j = 0; j < 8; ++j) tile[(dc * 16 + j) * 72 + ptl] = (unsigned short)s0[j];
#pragma unroll
    for (int j = 0; j < 8; ++j) tile[(dc * 16 + 8 + j) * 72 + ptl] = (unsigned short)s1[j];
    __syncthreads();

    const int d = threadIdx.x >> 2;
    const int tc = threadIdx.x & 3;
    short8 r0 = *(const short8*)&tile[d * 72 + tc * 16];
    short8 r1 = *(const short8*)&tile[d * 72 + tc * 16 + 8];
    unsigned short* dst = vt + ((size_t)bh * 64 + d) * T + t0 + tc * 16;
    *(short8*)dst = r0;
    *(short8*)(dst + 8) = r1;
}

// ---------------- MFMA flash attention ----------------
// R18 verbatim: QTILE=128, 8 waves (512 threads); KTL=64 keys/tile. K/V
// staged in LDS (load-after-barrier, spread over 512 threads); base-2
// softmax (log2e pre-folded into Q), DPP max+sum, cvt_pk_bf16 P rounding.
#define QTILE 128
#define KTL 64
#define KSTR 72

__global__ __launch_bounds__(512) void attn_mfma(const float* __restrict__ Q,
    const unsigned short* __restrict__ Khl, const unsigned short* __restrict__ vt,
    unsigned short* __restrict__ Ybf)
{
    constexpr int T = 2048, C = 1024;
    __shared__ __align__(16) unsigned short Ks_hi[KTL * KSTR];
    __shared__ __align__(16) unsigned short Ks_lo[KTL * KSTR];
    __shared__ __align__(16) unsigned short Vt[64 * KSTR];
    __shared__ __align__(16) unsigned short Ps[8][16 * KSTR];

    const int bh = blockIdx.y;
    const int h = bh & 15;
    const int b = bh >> 4;
    const int w = threadIdx.x >> 6;     // 0..7
    const int lane = threadIdx.x & 63;
    const int n16 = lane & 15;
    const int quad = lane >> 4;

    // Q A-fragments (hi/lo), loaded once and split.
    const int qrow = blockIdx.x * QTILE + w * 16 + n16;
    short8 qh[2], ql[2];
#pragma unroll
    for (int c = 0; c < 2; ++c) {
        const float* p = Q + ((size_t)(b * T + qrow)) * C + h * 64 + c * 32 + quad * 8;
        float4 f0 = *(const float4*)p;
        float4 f1 = *(const float4*)(p + 4);
        float f[8] = {f0.x, f0.y, f0.z, f0.w, f1.x, f1.y, f1.z, f1.w};
#pragma unroll
        for (int j = 0; j < 8; ++j) {
            unsigned short hb = bf16_rne(f[j]);
            float hf = __uint_as_float((unsigned)hb << 16);
            qh[c][j] = (short)hb;
            ql[c][j] = (short)bf16_rne(f[j] - hf);
        }
    }

    floatx4 o0 = {0,0,0,0}, o1 = {0,0,0,0}, o2 = {0,0,0,0}, o3 = {0,0,0,0};
    float mrow[4] = {-1e30f, -1e30f, -1e30f, -1e30f};
    float lrow[4] = {0.f, 0.f, 0.f, 0.f};

    // staging maps: 64 K rows (hi+lo) and 64 V dims over 512 threads,
    // 8-short chunks (1 b128 per buffer per thread)
    const unsigned short* khl = Khl + (((size_t)b * T) * 16 + h) * 128;
    const unsigned short* vtb = vt + (size_t)bh * 64 * T;
    const int sr = threadIdx.x >> 3;        // 0..63 (k-row / v-dim)
    const int sc = (threadIdx.x & 7) * 8;   // 0,8,...,56
    unsigned short* Pw = Ps[w];

    for (int kt = 0; kt < T; kt += KTL) {
        __syncthreads();
        {
            const unsigned short* src = khl + (size_t)(kt + sr) * 2048 + sc;
            *(short8*)&Ks_hi[sr * KSTR + sc] = *(const short8*)src;
            *(short8*)&Ks_lo[sr * KSTR + sc] = *(const short8*)(src + 64);
            const unsigned short* vsrc = vtb + (size_t)sr * T + kt + sc;
            *(short8*)&Vt[sr * KSTR + sc]    = *(const short8*)vsrc;
        }
        __syncthreads();

        // QK^T: 4 key groups x (2 chunks x 3 split-terms)
        floatx4 s0 = {0,0,0,0}, s1 = {0,0,0,0}, s2 = {0,0,0,0}, s3 = {0,0,0,0};
#pragma unroll
        for (int c = 0; c < 2; ++c) {
            const int ko = c * 32 + quad * 8;
            short8 kh, kl;
            kh = *(const short8*)&Ks_hi[n16 * KSTR + ko];
            kl = *(const short8*)&Ks_lo[n16 * KSTR + ko];
            s0 = mfma_bf16(qh[c], kh, s0); s0 = mfma_bf16(qh[c], kl, s0); s0 = mfma_bf16(ql[c], kh, s0);
            kh = *(const short8*)&Ks_hi[(16 + n16) * KSTR + ko];
            kl = *(const short8*)&Ks_lo[(16 + n16) * KSTR + ko];
            s1 = mfma_bf16(qh[c], kh, s1); s1 = mfma_bf16(qh[c], kl, s1); s1 = mfma_bf16(ql[c], kh, s1);
            kh = *(const short8*)&Ks_hi[(32 + n16) * KSTR + ko];
            kl = *(const short8*)&Ks_lo[(32 + n16) * KSTR + ko];
            s2 = mfma_bf16(qh[c], kh, s2); s2 = mfma_bf16(qh[c], kl, s2); s2 = mfma_bf16(ql[c], kh, s2);
            kh = *(const short8*)&Ks_hi[(48 + n16) * KSTR + ko];
            kl = *(const short8*)&Ks_lo[(48 + n16) * KSTR + ko];
            s3 = mfma_bf16(qh[c], kh, s3); s3 = mfma_bf16(qh[c], kl, s3); s3 = mfma_bf16(ql[c], kh, s3);
        }

        // online softmax, base-2 (log2e folded into Q): exp2 via v_exp_f32.
        // P for row (quad*4+r): scores for keys {g*16+n16} land at storage
        // column 4*n16+g -> 4 consecutive shorts -> packed b64 write.
#pragma unroll
        for (int r = 0; r < 4; ++r) {
            float mx = fmaxf(fmaxf(s0[r], s1[r]), fmaxf(s2[r], s3[r]));
            mx = row_max16(mx);
            float mn = fmaxf(mrow[r], mx);
            float fac = __builtin_amdgcn_exp2f(mrow[r] - mn);
            mrow[r] = mn;
            float p0 = __builtin_amdgcn_exp2f(s0[r] - mn);
            float p1 = __builtin_amdgcn_exp2f(s1[r] - mn);
            float p2 = __builtin_amdgcn_exp2f(s2[r] - mn);
            float p3 = __builtin_amdgcn_exp2f(s3[r] - mn);
            float s = row_sum16(((p0 + p1) + (p2 + p3)));
            lrow[r] = lrow[r] * fac + s;
            o0[r] *= fac; o1[r] *= fac; o2[r] *= fac; o3[r] *= fac;
            uint2 pk;
            pk.x = cvt_pk_bf16(p0, p1);
            pk.y = cvt_pk_bf16(p2, p3);
            *(uint2*)&Pw[(quad * 4 + r) * KSTR + (n16 << 2)] = pk;
        }

        // PV: keys 0..31 via pa0, 32..63 via pa1 (permuted storage order,
        // matching permuted V columns)
        {
            short8 pa0 = *(const short8*)&Pw[n16 * KSTR + quad * 8];
            short8 pa1 = *(const short8*)&Pw[n16 * KSTR + 32 + quad * 8];
            short8 v0, v1;
            v0 = *(const short8*)&Vt[n16 * KSTR + quad * 8];
            v1 = *(const short8*)&Vt[n16 * KSTR + 32 + quad * 8];
            o0 = mfma_bf16(pa0, v0, o0); o0 = mfma_bf16(pa1, v1, o0);
            v0 = *(const short8*)&Vt[(16 + n16) * KSTR + quad * 8];
            v1 = *(const short8*)&Vt[(16 + n16) * KSTR + 32 + quad * 8];
            o1 = mfma_bf16(pa0, v0, o1); o1 = mfma_bf16(pa1, v1, o1);
            v0 = *(const short8*)&Vt[(32 + n16) * KSTR + quad * 8];
            v1 = *(const short8*)&Vt[(32 + n16) * KSTR + 32 + quad * 8];
            o2 = mfma_bf16(pa0, v0, o2); o2 = mfma_bf16(pa1, v1, o2);
            v0 = *(const short8*)&Vt[(48 + n16) * KSTR + quad * 8];
            v1 = *(const short8*)&Vt[(48 + n16) * KSTR + 32 + quad * 8];
            o3 = mfma_bf16(pa0, v0, o3); o3 = mfma_bf16(pa1, v1, o3);
        }
    }

    // epilogue: normalize, write Y as bf16
#pragma unroll
    for (int r = 0; r < 4; ++r) {
        float inv = 1.0f / lrow[r];
        int row = blockIdx.x * QTILE + w * 16 + quad * 4 + r;
        unsigned short* yp = Ybf + (size_t)(b * T + row) * C + h * 64 + n16;
        yp[0]  = bf16_rne(o0[r] * inv);
        yp[16] = bf16_rne(o1[r] * inv);
        yp[32] = bf16_rne(o2[r] * inv);
        yp[48] = bf16_rne(o3[r] * inv);
    }
}

extern "C" void kernel_launch(void* const* d_in, const int* in_sizes, int n_in,
                              void* d_out, int out_size, void* d_ws, size_t ws_size,
                              hipStream_t stream)
{
    const float* x    = (const float*)d_in[0];
    const float* Wq   = (const float*)d_in[1];
    const float* Wk   = (const float*)d_in[2];
    const float* Wv   = (const float*)d_in[3];
    const float* Wo   = (const float*)d_in[4];
    const float* s_qk = (const float*)d_in[5];
    float* out = (float*)d_out;

    constexpr int B = 2, T = 2048, C = 1024, H = 16;
    constexpr int M = B * T;

    // workspace map (64 MB, phase-aliased):
    //  [0,16M)   Qb fp32 (rope in place)
    //  [16,32M)  Kf fp32 -> Khl bf16 hi|lo (rope, in place)
    //  [32,40M)  Vbf bf16 [t][C]
    //  [40,48M)  xh (dies after mgemm_qkv) -> tab (rope) -> vt [bh][d][t]
    //  [48,56M)  xl (dies after mgemm_qkv) -> Ybf bf16
    //  [56,64M)  Wqh,Wql,Wkh,Wkl (die after mgemm_qkv)
    char* ws = (char*)d_ws;
    float* Qb           = (float*)ws;
    float* Kf           = (float*)(ws + ((size_t)16 << 20));
    unsigned short* Khl = (unsigned short*)Kf;
    unsigned short* Vbf = (unsigned short*)(ws + ((size_t)32 << 20));
    unsigned short* xh  = (unsigned short*)(ws + ((size_t)40 << 20));
    unsigned short* xl  = (unsigned short*)(ws + ((size_t)48 << 20));
    unsigned short* vt  = xh;                     // after mgemm_qkv
    unsigned short* Ybf = xl;                     // after mgemm_qkv
    float2* tab         = (float2*)xh;            // between mgemm_qkv and vtrans
    unsigned short* Wqh = (unsigned short*)(ws + ((size_t)56 << 20));
    unsigned short* Wql = Wqh + (1u << 20);
    unsigned short* Wkh = Wql + (1u << 20);
    unsigned short* Wkl = Wkh + (1u << 20);

    dim3 blk(256);

    split_hl3<<<dim3(3072), blk, 0, stream>>>(x, Wq, Wk, xh, xl,
                                              Wqh, Wql, Wkh, Wkl);

    mgemm_qkv<<<dim3(M / 128, C / 128, 3), blk, 0, stream>>>(
        xh, xl, Wqh, Wql, Wkh, Wkl, Wv, Qb, Kf, Vbf);

    rope_table<<<dim3(T * 32 / 256), blk, 0, stream>>>(tab);
    rope_norm<<<dim3(2 * B * T * H / 4), blk, 0, stream>>>(Qb, Khl, s_qk, tab);
    vtrans<<<dim3(T / 64, B * H), blk, 0, stream>>>(Vbf, vt);

    attn_mfma<<<dim3(T / QTILE, B * H), dim3(512), 0, stream>>>(Qb, Khl, vt, Ybf);

    mgemm_o<<<dim3(M / 128, C / 128), blk, 0, stream>>>(Ybf, Wo, out);
}

// Round 12
// 293.031 us; speedup vs baseline: 1.0701x; 1.0497x over previous
//
#include <hip/hip_runtime.h>
#include <math.h>

// nGPT attention. B=2, T=2048, C=1024, H=16, D=64.
// R22 = R18 (best: 301.5us) + mgemm_o W pre-conversion.
//   mgemm3 gload_lds family REVERTED (R20 +12us, R21 dbuf +6us vs R18's
//   register-prefetch: instruction-count win never beat full-tile latency
//   cover + 3 blocks/CU). mgemm3/mgemm_qkv/attn = R18 verbatim.
//   NEW: wo_split converts Wo fp32->bf16 once (into dead Wqh region, after
//   mgemm_qkv); mgemm_o uses mgemm2_body = R18 mgemm3's proven pure-copy
//   register-prefetch staging (2 buffers). Removes ~64 VALU conversion ops
//   per thread-K-step from mgemm_o and halves its W-side global bytes.
//   Bit-identical numerics (same RNE conversion, applied once).
// R18/R15 kept: QTILE=128 8-wave attn (~115us structural floor), merged
// split_hl3, permuted-key P store, base-2 softmax, DPP max+sum.

typedef short short8 __attribute__((ext_vector_type(8)));
typedef float floatx4 __attribute__((ext_vector_type(4)));

__device__ __forceinline__ unsigned short bf16_rne(float x) {
    unsigned u = __float_as_uint(x);
    u += 0x7FFF + ((u >> 16) & 1);
    return (unsigned short)(u >> 16);
}

__device__ __forceinline__ unsigned cvt_pk_bf16(float lo, float hi) {
    unsigned r;
    asm("v_cvt_pk_bf16_f32 %0, %1, %2" : "=v"(r) : "v"(lo), "v"(hi));
    return r;
}

__device__ __forceinline__ floatx4 mfma_bf16(short8 a, short8 b, floatx4 c) {
    asm("v_mfma_f32_16x16x32_bf16 %0, %1, %2, %0" : "+v"(c) : "v"(a), "v"(b));
    return c;
}

// ---- DPP 16-lane butterfly reductions (VALU pipe) ----
template<int CTRL>
__device__ __forceinline__ float dpp_mov_f(float x) {
    return __int_as_float(__builtin_amdgcn_update_dpp(
        __float_as_int(x), __float_as_int(x), CTRL, 0xF, 0xF, false));
}
__device__ __forceinline__ float row_max16(float x) {
    x = fmaxf(x, dpp_mov_f<0xB1>(x));    // quad_perm(1,0,3,2)
    x = fmaxf(x, dpp_mov_f<0x4E>(x));    // quad_perm(2,3,0,1)
    x = fmaxf(x, dpp_mov_f<0x141>(x));   // row_half_mirror
    x = fmaxf(x, dpp_mov_f<0x140>(x));   // row_mirror
    return x;
}
__device__ __forceinline__ float row_sum16(float x) {
    x += dpp_mov_f<0xB1>(x);
    x += dpp_mov_f<0x4E>(x);
    x += dpp_mov_f<0x141>(x);
    x += dpp_mov_f<0x140>(x);
    return x;
}

// ------- fp32 -> bf16 hi/lo split, merged 3-input version (x, Wq, Wk) -------
__global__ __launch_bounds__(256) void split_hl3(
    const float* __restrict__ x, const float* __restrict__ Wq,
    const float* __restrict__ Wk,
    unsigned short* __restrict__ xh, unsigned short* __restrict__ xl,
    unsigned short* __restrict__ Wqh, unsigned short* __restrict__ Wql,
    unsigned short* __restrict__ Wkh, unsigned short* __restrict__ Wkl)
{
    const int bid = blockIdx.x;   // x: [0,2048) Wq: [2048,2560) Wk: [2560,3072)
    const float* src;
    unsigned short* hi;
    unsigned short* lo;
    size_t base;
    if (bid < 2048)      { src = x;  hi = xh;  lo = xl;  base = (size_t)bid * 2048; }
    else if (bid < 2560) { src = Wq; hi = Wqh; lo = Wql; base = (size_t)(bid - 2048) * 2048; }
    else                 { src = Wk; hi = Wkh; lo = Wkl; base = (size_t)(bid - 2560) * 2048; }
    size_t i = base + (size_t)threadIdx.x * 8;
    float4 f0 = *(const float4*)(src + i);
    float4 f1 = *(const float4*)(src + i + 4);
    float f[8] = {f0.x, f0.y, f0.z, f0.w, f1.x, f1.y, f1.z, f1.w};
    short8 h, l;
#pragma unroll
    for (int j = 0; j < 8; ++j) {
        unsigned short hb = bf16_rne(f[j]);
        h[j] = (short)hb;
        l[j] = (short)bf16_rne(f[j] - __uint_as_float((unsigned)hb << 16));
    }
    *(short8*)(hi + i) = h;
    *(short8*)(lo + i) = l;
}

// ------- fp32 -> bf16 (hi only), for Wo pre-conversion -------
__global__ __launch_bounds__(256) void wo_split(const float* __restrict__ src,
                                                unsigned short* __restrict__ dst)
{
    size_t i = ((size_t)blockIdx.x * 256 + threadIdx.x) * 8;
    float4 f0 = *(const float4*)(src + i);
    float4 f1 = *(const float4*)(src + i + 4);
    float f[8] = {f0.x, f0.y, f0.z, f0.w, f1.x, f1.y, f1.z, f1.w};
    short8 h;
#pragma unroll
    for (int j = 0; j < 8; ++j) h[j] = (short)bf16_rne(f[j]);
    *(short8*)(dst + i) = h;
}

// ---------------- MFMA GEMM bodies ----------------
#define LSTR 40   // shorts per LDS row (32 + 8 pad)

// 3-term bf16x3: C = Ah@Bh^T + Ah@Bl^T + Al@Bh^T, all inputs pre-split bf16.
// R18 verbatim: register-prefetch pure-copy staging, 2 barriers/K-step.
__device__ __forceinline__ void mgemm3_body(unsigned short* lds,
    const unsigned short* __restrict__ Ah, const unsigned short* __restrict__ Al,
    const unsigned short* __restrict__ Bh, const unsigned short* __restrict__ Bl,
    float* __restrict__ Cm, int bm, int bn)
{
    constexpr int Kd = 1024, Nd = 1024;
    unsigned short* LAh = lds;
    unsigned short* LBh = lds + 128 * LSTR;
    unsigned short* LAl = lds + 2 * 128 * LSTR;
    unsigned short* LBl = lds + 3 * 128 * LSTR;

    const int tid = threadIdx.x;
    const int srow = tid >> 1, skc = (tid & 1) << 4;
    const unsigned short* pah = Ah + (size_t)(bm + srow) * Kd + skc;
    const unsigned short* pal = Al + (size_t)(bm + srow) * Kd + skc;
    const unsigned short* pbh = Bh + (size_t)(bn + srow) * Kd + skc;
    const unsigned short* pbl = Bl + (size_t)(bn + srow) * Kd + skc;
    unsigned short* dah = &LAh[srow * LSTR + skc];
    unsigned short* dal = &LAl[srow * LSTR + skc];
    unsigned short* dbh = &LBh[srow * LSTR + skc];
    unsigned short* dbl = &LBl[srow * LSTR + skc];

    const int lane = tid & 63, w = tid >> 6;
    const int n16 = lane & 15, quad = lane >> 4;
    const int m0 = (w & 1) << 6, n0 = (w >> 1) << 6;

    floatx4 acc[4][4];
#pragma unroll
    for (int j = 0; j < 4; ++j)
#pragma unroll
        for (int i = 0; i < 4; ++i) acc[j][i] = (floatx4){0.f, 0.f, 0.f, 0.f};

    short8 rah0 = *(const short8*)(pah),     rah1 = *(const short8*)(pah + 8);
    short8 ral0 = *(const short8*)(pal),     ral1 = *(const short8*)(pal + 8);
    short8 rbh0 = *(const short8*)(pbh),     rbh1 = *(const short8*)(pbh + 8);
    short8 rbl0 = *(const short8*)(pbl),     rbl1 = *(const short8*)(pbl + 8);

    for (int kt = 0; kt < Kd; kt += 32) {
        __syncthreads();
        *(short8*)dah = rah0; *(short8*)(dah + 8) = rah1;
        *(short8*)dal = ral0; *(short8*)(dal + 8) = ral1;
        *(short8*)dbh = rbh0; *(short8*)(dbh + 8) = rbh1;
        *(short8*)dbl = rbl0; *(short8*)(dbl + 8) = rbl1;
        __syncthreads();
        if (kt + 32 < Kd) {
            rah0 = *(const short8*)(pah + kt + 32); rah1 = *(const short8*)(pah + kt + 40);
            ral0 = *(const short8*)(pal + kt + 32); ral1 = *(const short8*)(pal + kt + 40);
            rbh0 = *(const short8*)(pbh + kt + 32); rbh1 = *(const short8*)(pbh + kt + 40);
            rbl0 = *(const short8*)(pbl + kt + 32); rbl1 = *(const short8*)(pbl + kt + 40);
        }
        short8 ah[4], al[4];
#pragma unroll
        for (int i = 0; i < 4; ++i) {
            ah[i] = *(const short8*)&LAh[(m0 + i * 16 + n16) * LSTR + quad * 8];
            al[i] = *(const short8*)&LAl[(m0 + i * 16 + n16) * LSTR + quad * 8];
        }
#pragma unroll
        for (int j = 0; j < 4; ++j) {
            short8 bh = *(const short8*)&LBh[(n0 + j * 16 + n16) * LSTR + quad * 8];
            short8 bl = *(const short8*)&LBl[(n0 + j * 16 + n16) * LSTR + quad * 8];
#pragma unroll
            for (int i = 0; i < 4; ++i) {
                acc[j][i] = mfma_bf16(ah[i], bh, acc[j][i]);
                acc[j][i] = mfma_bf16(ah[i], bl, acc[j][i]);
                acc[j][i] = mfma_bf16(al[i], bh, acc[j][i]);
            }
        }
    }

#pragma unroll
    for (int j = 0; j < 4; ++j)
#pragma unroll
        for (int i = 0; i < 4; ++i) {
            float* cp = Cm + (size_t)(bm + m0 + i * 16 + quad * 4) * Nd
                        + bn + n0 + j * 16 + n16;
#pragma unroll
            for (int r = 0; r < 4; ++r)
                cp[(size_t)r * Nd] = acc[j][i][r];
        }
}

// 1-term bf16: A pre-converted bf16, W fp32 converted in staging (Wv path).
template<bool OUT16>
__device__ __forceinline__ void mgemm1_body(unsigned short* lds,
    const unsigned short* __restrict__ Abf, const float* __restrict__ Wf,
    void* __restrict__ Out, int bm, int bn)
{
    constexpr int Kd = 1024, Nd = 1024;
    unsigned short* LA = lds;
    unsigned short* LB = lds + 128 * LSTR;

    const int tid = threadIdx.x;
    const int srow = tid >> 1, skc = (tid & 1) << 4;
    const unsigned short* pa = Abf + (size_t)(bm + srow) * Kd + skc;
    const float* pw = Wf + (size_t)(bn + srow) * Kd + skc;
    unsigned short* da = &LA[srow * LSTR + skc];
    unsigned short* db = &LB[srow * LSTR + skc];

    const int lane = tid & 63, w = tid >> 6;
    const int n16 = lane & 15, quad = lane >> 4;
    const int m0 = (w & 1) << 6, n0 = (w >> 1) << 6;

    floatx4 acc[4][4];
#pragma unroll
    for (int j = 0; j < 4; ++j)
#pragma unroll
        for (int i = 0; i < 4; ++i) acc[j][i] = (floatx4){0.f, 0.f, 0.f, 0.f};

    short8 ra0 = *(const short8*)(pa), ra1 = *(const short8*)(pa + 8);
    float4 w0 = *(const float4*)(pw),      w1 = *(const float4*)(pw + 4);
    float4 w2 = *(const float4*)(pw + 8),  w3 = *(const float4*)(pw + 12);

    for (int kt = 0; kt < Kd; kt += 32) {
        float fw[16];
        *(float4*)&fw[0] = w0; *(float4*)&fw[4] = w1;
        *(float4*)&fw[8] = w2; *(float4*)&fw[12] = w3;
        short8 h0, h1;
#pragma unroll
        for (int j = 0; j < 8; ++j) {
            h0[j] = (short)bf16_rne(fw[j]);
            h1[j] = (short)bf16_rne(fw[8 + j]);
        }
        __syncthreads();
        *(short8*)da = ra0; *(short8*)(da + 8) = ra1;
        *(short8*)db = h0;  *(short8*)(db + 8) = h1;
        __syncthreads();
        if (kt + 32 < Kd) {
            ra0 = *(const short8*)(pa + kt + 32); ra1 = *(const short8*)(pa + kt + 40);
            w0 = *(const float4*)(pw + kt + 32);  w1 = *(const float4*)(pw + kt + 36);
            w2 = *(const float4*)(pw + kt + 40);  w3 = *(const float4*)(pw + kt + 44);
        }
        short8 ah[4];
#pragma unroll
        for (int i = 0; i < 4; ++i)
            ah[i] = *(const short8*)&LA[(m0 + i * 16 + n16) * LSTR + quad * 8];
#pragma unroll
        for (int j = 0; j < 4; ++j) {
            short8 bh = *(const short8*)&LB[(n0 + j * 16 + n16) * LSTR + quad * 8];
#pragma unroll
            for (int i = 0; i < 4; ++i)
                acc[j][i] = mfma_bf16(ah[i], bh, acc[j][i]);
        }
    }

#pragma unroll
    for (int j = 0; j < 4; ++j)
#pragma unroll
        for (int i = 0; i < 4; ++i) {
            size_t base = (size_t)(bm + m0 + i * 16 + quad * 4) * Nd
                          + bn + n0 + j * 16 + n16;
            if (OUT16) {
                unsigned short* cp = (unsigned short*)Out + base;
#pragma unroll
                for (int r = 0; r < 4; ++r)
                    cp[(size_t)r * Nd] = bf16_rne(acc[j][i][r]);
            } else {
                float* cp = (float*)Out + base;
#pragma unroll
                for (int r = 0; r < 4; ++r)
                    cp[(size_t)r * Nd] = acc[j][i][r];
            }
        }
}

// 1-term bf16, BOTH operands pre-converted bf16: pure-copy register-prefetch
// staging (R18 mgemm3 pattern, 2 buffers). Used by mgemm_o.
__device__ __forceinline__ void mgemm2_body(unsigned short* lds,
    const unsigned short* __restrict__ Abf, const unsigned short* __restrict__ Wbf,
    float* __restrict__ Out, int bm, int bn)
{
    constexpr int Kd = 1024, Nd = 1024;
    unsigned short* LA = lds;
    unsigned short* LB = lds + 128 * LSTR;

    const int tid = threadIdx.x;
    const int srow = tid >> 1, skc = (tid & 1) << 4;
    const unsigned short* pa = Abf + (size_t)(bm + srow) * Kd + skc;
    const unsigned short* pb = Wbf + (size_t)(bn + srow) * Kd + skc;
    unsigned short* da = &LA[srow * LSTR + skc];
    unsigned short* db = &LB[srow * LSTR + skc];

    const int lane = tid & 63, w = tid >> 6;
    const int n16 = lane & 15, quad = lane >> 4;
    const int m0 = (w & 1) << 6, n0 = (w >> 1) << 6;

    floatx4 acc[4][4];
#pragma unroll
    for (int j = 0; j < 4; ++j)
#pragma unroll
        for (int i = 0; i < 4; ++i) acc[j][i] = (floatx4){0.f, 0.f, 0.f, 0.f};

    short8 ra0 = *(const short8*)(pa), ra1 = *(const short8*)(pa + 8);
    short8 rb0 = *(const short8*)(pb), rb1 = *(const short8*)(pb + 8);

    for (int kt = 0; kt < Kd; kt += 32) {
        __syncthreads();
        *(short8*)da = ra0; *(short8*)(da + 8) = ra1;
        *(short8*)db = rb0; *(short8*)(db + 8) = rb1;
        __syncthreads();
        if (kt + 32 < Kd) {
            ra0 = *(const short8*)(pa + kt + 32); ra1 = *(const short8*)(pa + kt + 40);
            rb0 = *(const short8*)(pb + kt + 32); rb1 = *(const short8*)(pb + kt + 40);
        }
        short8 ah[4];
#pragma unroll
        for (int i = 0; i < 4; ++i)
            ah[i] = *(const short8*)&LA[(m0 + i * 16 + n16) * LSTR + quad * 8];
#pragma unroll
        for (int j = 0; j < 4; ++j) {
            short8 bh = *(const short8*)&LB[(n0 + j * 16 + n16) * LSTR + quad * 8];
#pragma unroll
            for (int i = 0; i < 4; ++i)
                acc[j][i] = mfma_bf16(ah[i], bh, acc[j][i]);
        }
    }

#pragma unroll
    for (int j = 0; j < 4; ++j)
#pragma unroll
        for (int i = 0; i < 4; ++i) {
            float* cp = Out + (size_t)(bm + m0 + i * 16 + quad * 4) * Nd
                        + bn + n0 + j * 16 + n16;
#pragma unroll
            for (int r = 0; r < 4; ++r)
                cp[(size_t)r * Nd] = acc[j][i][r];
        }
}

__global__ __launch_bounds__(256) void mgemm_qkv(
    const unsigned short* __restrict__ xh, const unsigned short* __restrict__ xl,
    const unsigned short* __restrict__ Wqh, const unsigned short* __restrict__ Wql,
    const unsigned short* __restrict__ Wkh, const unsigned short* __restrict__ Wkl,
    const float* __restrict__ Wv,
    float* __restrict__ Qb, float* __restrict__ Kf, unsigned short* __restrict__ Vbf)
{
    __shared__ __align__(16) unsigned short lds[4 * 128 * LSTR];   // 40 KB
    const int bm = blockIdx.x * 128, bn = blockIdx.y * 128;
    if (blockIdx.z == 2)      mgemm1_body<true>(lds, xh, Wv, Vbf, bm, bn);
    else if (blockIdx.z == 0) mgemm3_body(lds, xh, xl, Wqh, Wql, Qb, bm, bn);
    else                      mgemm3_body(lds, xh, xl, Wkh, Wkl, Kf, bm, bn);
}

__global__ __launch_bounds__(256) void mgemm_o(const unsigned short* __restrict__ Ybf,
    const unsigned short* __restrict__ Wob, float* __restrict__ Out)
{
    __shared__ __align__(16) unsigned short lds[2 * 128 * LSTR];   // 20 KB
    mgemm2_body(lds, Ybf, Wob, Out, blockIdx.x * 128, blockIdx.y * 128);
}

// ---------------- RoPE ----------------
__global__ __launch_bounds__(256) void rope_table(float2* __restrict__ tab)
{
    int idx = blockIdx.x * 256 + threadIdx.x;   // t*32 + p
    int t = idx >> 5, p = idx & 31;
    double invf = pow(10000.0, -(double)p / 32.0);
    double sd, cd;
    sincos((double)t * invf, &sd, &cd);
    tab[idx] = make_float2((float)cd, (float)sd);
}

// One wave per (b,t,h,{q|k}); lane = d. RoPE + L2-normalize + scale.
// Q: in-place fp32 (sqrt(D)=8 and log2(e) folded -> base-2 softmax).
// K: bf16 hi|lo over its own fp32 row.
__global__ __launch_bounds__(256) void rope_norm(float* __restrict__ Q,
                                                 unsigned short* __restrict__ Khl,
                                                 const float* __restrict__ s_qk,
                                                 const float2* __restrict__ tab)
{
    constexpr int T = 2048, H = 16;
    int wid = blockIdx.x * 4 + (threadIdx.x >> 6);
    const int lane = threadIdx.x & 63;
    const int sel = wid & 1; wid >>= 1;
    const int h = wid & (H - 1); wid >>= 4;
    const int t = wid & (T - 1); wid >>= 11;
    const int b = wid;

    const size_t idx = ((size_t)(b * T + t)) * H + h;
    float v = sel ? ((const float*)Khl)[idx * 64 + lane] : Q[idx * 64 + lane];

    float2 cs2 = tab[(t << 5) + (lane >> 1)];
    const float cs = cs2.x, sn = cs2.y;

    float partner = __shfl_xor(v, 1, 64);
    float rot = (lane & 1) ? partner : -partner;
    float r = v * cs + rot * sn;

    float ssq = r * r;
#pragma unroll
    for (int off = 32; off; off >>= 1) ssq += __shfl_xor(ssq, off, 64);
    float nrm = fmaxf(sqrtf(ssq), 1e-12f);

    float scale = s_qk[h * 64 + lane] * 32.0f;   // s_qk * sqrt(C)
    if (!sel) {
        // fold sqrt(D)=8 and log2(e) into Q -> attn scores are base-2
        Q[idx * 64 + lane] = r / nrm * (scale * 8.0f * 1.44269504088896340736f);
    } else {
        float val = r / nrm * scale;
        unsigned short hi = bf16_rne(val);
        unsigned short lo = bf16_rne(val - __uint_as_float((unsigned)hi << 16));
        unsigned short* row = Khl + idx * 128;
        row[lane] = hi;
        row[64 + lane] = lo;
    }
}

// ---------------- V transpose: Vbf[t][h*64+d] -> vt[bh][d][t] (bf16) --------
// Key order PERMUTED within each 64-key block: original key k (k = t mod 64)
// is stored at position 4*(k%16) + (k/16). This matches the attn C-layout of
// QK^T (lane(quad,n16) holds scores for keys {g*16+n16, g=0..3}) so P can be
// packed and written as one ds_write_b64 per row. PV contracts P and V over
// the same permuted storage index -> result unchanged.
__global__ __launch_bounds__(256) void vtrans(const unsigned short* __restrict__ Vbf,
                                              unsigned short* __restrict__ vt)
{
    constexpr int T = 2048, C = 1024;
    __shared__ unsigned short tile[64 * 72];
    const int bh = blockIdx.y;
    const int h = bh & 15, b = bh >> 4;
    const int t0 = blockIdx.x * 64;

    const int tl = threadIdx.x & 63;
    const int dc = threadIdx.x >> 6;
    const int ptl = ((tl & 15) << 2) | (tl >> 4);   // permuted key position
    const unsigned short* src = Vbf + (size_t)(b * T + t0 + tl) * C + h * 64 + dc * 16;
    short8 s0 = *(const short8*)src;
    short8 s1 = *(const short8*)(src + 8);
#pragma unroll
    for (int j = 0; j < 8; ++j) tile[(dc * 16 + j) * 72 + ptl] = (unsigned short)s0[j];
#pragma unroll
    for (int j = 0; j < 8; ++j) tile[(dc * 16 + 8 + j) * 72 + ptl] = (unsigned short)s1[j];
    __syncthreads();

    const int d = threadIdx.x >> 2;
    const int tc = threadIdx.x & 3;
    short8 r0 = *(const short8*)&tile[d * 72 + tc * 16];
    short8 r1 = *(const short8*)&tile[d * 72 + tc * 16 + 8];
    unsigned short* dst = vt + ((size_t)bh * 64 + d) * T + t0 + tc * 16;
    *(short8*)dst = r0;
    *(short8*)(dst + 8) = r1;
}

// ---------------- MFMA flash attention ----------------
// R18 verbatim: QTILE=128, 8 waves (512 threads); KTL=64 keys/tile. K/V
// staged in LDS (load-after-barrier, spread over 512 threads); base-2
// softmax (log2e pre-folded into Q), DPP max+sum, cvt_pk_bf16 P rounding.
#define QTILE 128
#define KTL 64
#define KSTR 72

__global__ __launch_bounds__(512) void attn_mfma(const float* __restrict__ Q,
    const unsigned short* __restrict__ Khl, const unsigned short* __restrict__ vt,
    unsigned short* __restrict__ Ybf)
{
    constexpr int T = 2048, C = 1024;
    __shared__ __align__(16) unsigned short Ks_hi[KTL * KSTR];
    __shared__ __align__(16) unsigned short Ks_lo[KTL * KSTR];
    __shared__ __align__(16) unsigned short Vt[64 * KSTR];
    __shared__ __align__(16) unsigned short Ps[8][16 * KSTR];

    const int bh = blockIdx.y;
    const int h = bh & 15;
    const int b = bh >> 4;
    const int w = threadIdx.x >> 6;     // 0..7
    const int lane = threadIdx.x & 63;
    const int n16 = lane & 15;
    const int quad = lane >> 4;

    // Q A-fragments (hi/lo), loaded once and split.
    const int qrow = blockIdx.x * QTILE + w * 16 + n16;
    short8 qh[2], ql[2];
#pragma unroll
    for (int c = 0; c < 2; ++c) {
        const float* p = Q + ((size_t)(b * T + qrow)) * C + h * 64 + c * 32 + quad * 8;
        float4 f0 = *(const float4*)p;
        float4 f1 = *(const float4*)(p + 4);
        float f[8] = {f0.x, f0.y, f0.z, f0.w, f1.x, f1.y, f1.z, f1.w};
#pragma unroll
        for (int j = 0; j < 8; ++j) {
            unsigned short hb = bf16_rne(f[j]);
            float hf = __uint_as_float((unsigned)hb << 16);
            qh[c][j] = (short)hb;
            ql[c][j] = (short)bf16_rne(f[j] - hf);
        }
    }

    floatx4 o0 = {0,0,0,0}, o1 = {0,0,0,0}, o2 = {0,0,0,0}, o3 = {0,0,0,0};
    float mrow[4] = {-1e30f, -1e30f, -1e30f, -1e30f};
    float lrow[4] = {0.f, 0.f, 0.f, 0.f};

    // staging maps: 64 K rows (hi+lo) and 64 V dims over 512 threads,
    // 8-short chunks (1 b128 per buffer per thread)
    const unsigned short* khl = Khl + (((size_t)b * T) * 16 + h) * 128;
    const unsigned short* vtb = vt + (size_t)bh * 64 * T;
    const int sr = threadIdx.x >> 3;        // 0..63 (k-row / v-dim)
    const int sc = (threadIdx.x & 7) * 8;   // 0,8,...,56
    unsigned short* Pw = Ps[w];

    for (int kt = 0; kt < T; kt += KTL) {
        __syncthreads();
        {
            const unsigned short* src = khl + (size_t)(kt + sr) * 2048 + sc;
            *(short8*)&Ks_hi[sr * KSTR + sc] = *(const short8*)src;
            *(short8*)&Ks_lo[sr * KSTR + sc] = *(const short8*)(src + 64);
            const unsigned short* vsrc = vtb + (size_t)sr * T + kt + sc;
            *(short8*)&Vt[sr * KSTR + sc]    = *(const short8*)vsrc;
        }
        __syncthreads();

        // QK^T: 4 key groups x (2 chunks x 3 split-terms)
        floatx4 s0 = {0,0,0,0}, s1 = {0,0,0,0}, s2 = {0,0,0,0}, s3 = {0,0,0,0};
#pragma unroll
        for (int c = 0; c < 2; ++c) {
            const int ko = c * 32 + quad * 8;
            short8 kh, kl;
            kh = *(const short8*)&Ks_hi[n16 * KSTR + ko];
            kl = *(const short8*)&Ks_lo[n16 * KSTR + ko];
            s0 = mfma_bf16(qh[c], kh, s0); s0 = mfma_bf16(qh[c], kl, s0); s0 = mfma_bf16(ql[c], kh, s0);
            kh = *(const short8*)&Ks_hi[(16 + n16) * KSTR + ko];
            kl = *(const short8*)&Ks_lo[(16 + n16) * KSTR + ko];
            s1 = mfma_bf16(qh[c], kh, s1); s1 = mfma_bf16(qh[c], kl, s1); s1 = mfma_bf16(ql[c], kh, s1);
            kh = *(const short8*)&Ks_hi[(32 + n16) * KSTR + ko];
            kl = *(const short8*)&Ks_lo[(32 + n16) * KSTR + ko];
            s2 = mfma_bf16(qh[c], kh, s2); s2 = mfma_bf16(qh[c], kl, s2); s2 = mfma_bf16(ql[c], kh, s2);
            kh = *(const short8*)&Ks_hi[(48 + n16) * KSTR + ko];
            kl = *(const short8*)&Ks_lo[(48 + n16) * KSTR + ko];
            s3 = mfma_bf16(qh[c], kh, s3); s3 = mfma_bf16(qh[c], kl, s3); s3 = mfma_bf16(ql[c], kh, s3);
        }

        // online softmax, base-2 (log2e folded into Q): exp2 via v_exp_f32.
        // P for row (quad*4+r): scores for keys {g*16+n16} land at storage
        // column 4*n16+g -> 4 consecutive shorts -> packed b64 write.
#pragma unroll
        for (int r = 0; r < 4; ++r) {
            float mx = fmaxf(fmaxf(s0[r], s1[r]), fmaxf(s2[r], s3[r]));
            mx = row_max16(mx);
            float mn = fmaxf(mrow[r], mx);
            float fac = __builtin_amdgcn_exp2f(mrow[r] - mn);
            mrow[r] = mn;
            float p0 = __builtin_amdgcn_exp2f(s0[r] - mn);
            float p1 = __builtin_amdgcn_exp2f(s1[r] - mn);
            float p2 = __builtin_amdgcn_exp2f(s2[r] - mn);
            float p3 = __builtin_amdgcn_exp2f(s3[r] - mn);
            float s = row_sum16(((p0 + p1) + (p2 + p3)));
            lrow[r] = lrow[r] * fac + s;
            o0[r] *= fac; o1[r] *= fac; o2[r] *= fac; o3[r] *= fac;
            uint2 pk;
            pk.x = cvt_pk_bf16(p0, p1);
            pk.y = cvt_pk_bf16(p2, p3);
            *(uint2*)&Pw[(quad * 4 + r) * KSTR + (n16 << 2)] = pk;
        }

        // PV: keys 0..31 via pa0, 32..63 via pa1 (permuted storage order,
        // matching permuted V columns)
        {
            short8 pa0 = *(const short8*)&Pw[n16 * KSTR + quad * 8];
            short8 pa1 = *(const short8*)&Pw[n16 * KSTR + 32 + quad * 8];
            short8 v0, v1;
            v0 = *(const short8*)&Vt[n16 * KSTR + quad * 8];
            v1 = *(const short8*)&Vt[n16 * KSTR + 32 + quad * 8];
            o0 = mfma_bf16(pa0, v0, o0); o0 = mfma_bf16(pa1, v1, o0);
            v0 = *(const short8*)&Vt[(16 + n16) * KSTR + quad * 8];
            v1 = *(const short8*)&Vt[(16 + n16) * KSTR + 32 + quad * 8];
            o1 = mfma_bf16(pa0, v0, o1); o1 = mfma_bf16(pa1, v1, o1);
            v0 = *(const short8*)&Vt[(32 + n16) * KSTR + quad * 8];
            v1 = *(const short8*)&Vt[(32 + n16) * KSTR + 32 + quad * 8];
            o2 = mfma_bf16(pa0, v0, o2); o2 = mfma_bf16(pa1, v1, o2);
            v0 = *(const short8*)&Vt[(48 + n16) * KSTR + quad * 8];
            v1 = *(const short8*)&Vt[(48 + n16) * KSTR + 32 + quad * 8];
            o3 = mfma_bf16(pa0, v0, o3); o3 = mfma_bf16(pa1, v1, o3);
        }
    }

    // epilogue: normalize, write Y as bf16
#pragma unroll
    for (int r = 0; r < 4; ++r) {
        float inv = 1.0f / lrow[r];
        int row = blockIdx.x * QTILE + w * 16 + quad * 4 + r;
        unsigned short* yp = Ybf + (size_t)(b * T + row) * C + h * 64 + n16;
        yp[0]  = bf16_rne(o0[r] * inv);
        yp[16] = bf16_rne(o1[r] * inv);
        yp[32] = bf16_rne(o2[r] * inv);
        yp[48] = bf16_rne(o3[r] * inv);
    }
}

extern "C" void kernel_launch(void* const* d_in, const int* in_sizes, int n_in,
                              void* d_out, int out_size, void* d_ws, size_t ws_size,
                              hipStream_t stream)
{
    const float* x    = (const float*)d_in[0];
    const float* Wq   = (const float*)d_in[1];
    const float* Wk   = (const float*)d_in[2];
    const float* Wv   = (const float*)d_in[3];
    const float* Wo   = (const float*)d_in[4];
    const float* s_qk = (const float*)d_in[5];
    float* out = (float*)d_out;

    constexpr int B = 2, T = 2048, C = 1024, H = 16;
    constexpr int M = B * T;

    // workspace map (64 MB, phase-aliased):
    //  [0,16M)   Qb fp32 (rope in place)
    //  [16,32M)  Kf fp32 -> Khl bf16 hi|lo (rope, in place)
    //  [32,40M)  Vbf bf16 [t][C]
    //  [40,48M)  xh (dies after mgemm_qkv) -> tab (rope) -> vt [bh][d][t]
    //  [48,56M)  xl (dies after mgemm_qkv) -> Ybf bf16
    //  [56,64M)  Wqh,Wql,Wkh,Wkl (die after mgemm_qkv) -> Wob (Wqh slot)
    char* ws = (char*)d_ws;
    float* Qb           = (float*)ws;
    float* Kf           = (float*)(ws + ((size_t)16 << 20));
    unsigned short* Khl = (unsigned short*)Kf;
    unsigned short* Vbf = (unsigned short*)(ws + ((size_t)32 << 20));
    unsigned short* xh  = (unsigned short*)(ws + ((size_t)40 << 20));
    unsigned short* xl  = (unsigned short*)(ws + ((size_t)48 << 20));
    unsigned short* vt  = xh;                     // after mgemm_qkv
    unsigned short* Ybf = xl;                     // after mgemm_qkv
    float2* tab         = (float2*)xh;            // between mgemm_qkv and vtrans
    unsigned short* Wqh = (unsigned short*)(ws + ((size_t)56 << 20));
    unsigned short* Wql = Wqh + (1u << 20);
    unsigned short* Wkh = Wql + (1u << 20);
    unsigned short* Wkl = Wkh + (1u << 20);
    unsigned short* Wob = Wqh;                    // after mgemm_qkv

    dim3 blk(256);

    split_hl3<<<dim3(3072), blk, 0, stream>>>(x, Wq, Wk, xh, xl,
                                              Wqh, Wql, Wkh, Wkl);

    mgemm_qkv<<<dim3(M / 128, C / 128, 3), blk, 0, stream>>>(
        xh, xl, Wqh, Wql, Wkh, Wkl, Wv, Qb, Kf, Vbf);

    wo_split<<<dim3(C * C / (256 * 8)), blk, 0, stream>>>(Wo, Wob);
    rope_table<<<dim3(T * 32 / 256), blk, 0, stream>>>(tab);
    rope_norm<<<dim3(2 * B * T * H / 4), blk, 0, stream>>>(Qb, Khl, s_qk, tab);
    vtrans<<<dim3(T / 64, B * H), blk, 0, stream>>>(Vbf, vt);

    attn_mfma<<<dim3(T / QTILE, B * H), dim3(512), 0, stream>>>(Qb, Khl, vt, Ybf);

    mgemm_o<<<dim3(M / 128, C / 128), blk, 0, stream>>>(Ybf, Wob, out);
}